// Round 6
// baseline (144.706 us; speedup 1.0000x reference)
//
#include <hip/hip_runtime.h>

typedef unsigned short u16;
typedef __bf16   bf16x8 __attribute__((ext_vector_type(8)));
typedef float    f32x4  __attribute__((ext_vector_type(4)));
typedef float    f32x16 __attribute__((ext_vector_type(16)));
typedef unsigned u32x4v __attribute__((ext_vector_type(4)));
typedef u16      u16x8  __attribute__((ext_vector_type(8)));

#define DEV __device__ __forceinline__

DEV u16 tobf(float f) {               // RNE via HW convert
  return __builtin_bit_cast(unsigned short, (__bf16)f);
}

DEV unsigned pack2(float a, float b) { // 2xf32 -> packed 2xbf16
  return (unsigned)tobf(a) | ((unsigned)tobf(b) << 16);
}

DEV f32x4 fzero() { f32x4 z; z[0]=0.f; z[1]=0.f; z[2]=0.f; z[3]=0.f; return z; }

DEV void async_cp16(void* lds, const void* g) {
  __builtin_amdgcn_global_load_lds(
      (const __attribute__((address_space(1))) void*)g,
      (__attribute__((address_space(3))) void*)lds, 16, 0, 0);
}

DEV void cvt8(const float* __restrict__ in, u16* __restrict__ out, int i) {
  const float4* in4 = (const float4*)in;
  float4 a = in4[2*i], b = in4[2*i+1];
  u16x8 r;
  r[0]=tobf(a.x); r[1]=tobf(a.y); r[2]=tobf(a.z); r[3]=tobf(a.w);
  r[4]=tobf(b.x); r[5]=tobf(b.y); r[6]=tobf(b.z); r[7]=tobf(b.w);
  *(u16x8*)(out + 8*(size_t)i) = r;
}

// ---------------- fused pre-pass: f32->bf16 converts + mask-nonzero OR -------
__global__ void k_zero_flag(unsigned* f) {
  if (threadIdx.x == 0 && blockIdx.x == 0) *f = 0u;
}

__global__ __launch_bounds__(256)
void k_pre(const float* __restrict__ x, const float* __restrict__ wqkv,
           const float* __restrict__ wproj,
           u16* __restrict__ xb, u16* __restrict__ wqkvb, u16* __restrict__ wprojb,
           const u32x4v* __restrict__ mask, unsigned* __restrict__ flag)
{
  const int tid = blockIdx.x * blockDim.x + threadIdx.x;
  const int stride = gridDim.x * blockDim.x;
  for (int i = tid; i < 524288; i += stride) cvt8(x, xb, i);
  for (int i = tid; i < 393216; i += stride) cvt8(wqkv, wqkvb, i);
  for (int i = tid; i < 131072; i += stride) cvt8(wproj, wprojb, i);
  unsigned o = 0;
  for (int i = tid; i < 2097152; i += stride) {
    u32x4v v = mask[i];
    o |= v[0] | v[1] | v[2] | v[3];
  }
  if (o & 0x7fffffffu) atomicOr(flag, 1u);         // ignore -0.0
}

// ---------------- NT GEMM: C[m,n] = sum_k A[m,k]*B[n,k], bf16 in, f32 acc ----
template<int EPI>
__global__ __launch_bounds__(256)
void k_gemm_nt(const u16* __restrict__ A, const u16* __restrict__ B,
               int N, int K, int nbn,
               const float* __restrict__ bq, const float* __restrict__ bk,
               const float* __restrict__ bv,
               u16* __restrict__ qo, u16* __restrict__ ko, u16* __restrict__ vto,
               float* __restrict__ fo, const float* __restrict__ bp)
{
  __shared__ u16 sA[2][4096];   // [128][32] bf16, chunk-swizzled
  __shared__ u16 sB[2][4096];

  const int tid  = threadIdx.x;
  const int lane = tid & 63;
  const int wave = tid >> 6;
  const int lr = lane & 15, lg = lane >> 4;
  const int wr = wave >> 1, wc = wave & 1;

  const int per = gridDim.x >> 3;
  const int bid = blockIdx.x;
  const int swz = (bid & 7) * per + (bid >> 3);
  const int bm0 = (swz / nbn) << 7;
  const int bn0 = (swz - (swz / nbn) * nbn) << 7;

  const size_t Kb = (size_t)K * 2;

  auto stage = [&](int buf, int kt) {
#pragma unroll
    for (int j = 0; j < 2; ++j) {
      int off = (tid + j * 256) << 4;
      int row = off >> 6;
      int ch  = (off & 63) >> 4;
      int gch = ch ^ (row & 3);
      async_cp16((char*)&sA[buf][0] + off,
                 (const char*)A + (size_t)(bm0 + row) * Kb + (size_t)kt * 64 + gch * 16);
      async_cp16((char*)&sB[buf][0] + off,
                 (const char*)B + (size_t)(bn0 + row) * Kb + (size_t)kt * 64 + gch * 16);
    }
  };

  f32x4 acc[4][4];
#pragma unroll
  for (int i = 0; i < 4; ++i)
#pragma unroll
    for (int j = 0; j < 4; ++j) acc[i][j] = fzero();

  const int nk = K >> 5;
  stage(0, 0);
  __syncthreads();

  for (int kt = 0; kt < nk; ++kt) {
    const int cur = kt & 1;
    if (kt + 1 < nk) stage(cur ^ 1, kt + 1);

    bf16x8 af[4], bfr[4];
#pragma unroll
    for (int mi = 0; mi < 4; ++mi) {
      int row = (wr << 6) + (mi << 4) + lr;
      int addr = (row << 6) + ((lg ^ (row & 3)) << 4);
      af[mi] = *(const bf16x8*)((const char*)&sA[cur][0] + addr);
    }
#pragma unroll
    for (int ni = 0; ni < 4; ++ni) {
      int row = (wc << 6) + (ni << 4) + lr;
      int addr = (row << 6) + ((lg ^ (row & 3)) << 4);
      bfr[ni] = *(const bf16x8*)((const char*)&sB[cur][0] + addr);
    }
#pragma unroll
    for (int mi = 0; mi < 4; ++mi)
#pragma unroll
      for (int ni = 0; ni < 4; ++ni)
        acc[mi][ni] = __builtin_amdgcn_mfma_f32_16x16x32_bf16(af[mi], bfr[ni], acc[mi][ni], 0, 0, 0);

    __syncthreads();
  }

#pragma unroll
  for (int mi = 0; mi < 4; ++mi) {
#pragma unroll
    for (int ni = 0; ni < 4; ++ni) {
      int col = bn0 + (wc << 6) + (ni << 4) + lr;
      if (EPI == 0) {
        int s = col >> 10, hd = col & 1023;
        int h = hd >> 6, d = hd & 63;
        float bias = (s == 0 ? bq[hd] : (s == 1 ? bk[hd] : bv[hd]));
#pragma unroll
        for (int r = 0; r < 4; ++r) {
          int m = bm0 + (wr << 6) + (mi << 4) + (lg << 2) + r;
          int b = m >> 11, n = m & 2047;
          float v = acc[mi][ni][r] + bias;
          if (s == 0) v *= 0.125f;            // fold hd^-0.5 into Q (exact pow2)
          u16 val = tobf(v);
          size_t bh = (size_t)(b * 16 + h);
          if (s == 0)      qo[(bh * 2048 + n) * 64 + d] = val;
          else if (s == 1) ko[(bh * 2048 + n) * 64 + d] = val;
          else             vto[(bh * 64 + d) * 2048 + n] = val;  // V transposed
        }
      } else {
        float bias = bp[col];
#pragma unroll
        for (int r = 0; r < 4; ++r) {
          int m = bm0 + (wr << 6) + (mi << 4) + (lg << 2) + r;
          fo[(size_t)m * N + col] = acc[mi][ni][r] + bias;
        }
      }
    }
  }
}

// ---------------- flash attention, 32x32 MFMA, KV-parity split ----------------
// grid = B*H*(N/128) = 512 blocks, 512 threads = 8 waves.
// Waves 0-3 (group 0) process even KV tiles, waves 4-7 (group 1) odd tiles;
// each group has its own double-buffered K/V LDS. Final flash-combine merges
// group 1's (O,m,l) into group 0 via lane-matched LDS exchange.
__global__ __launch_bounds__(512, 4)
void k_attn(const u16* __restrict__ qb, const u16* __restrict__ kb,
            const u16* __restrict__ vtb, u16* __restrict__ ao,
            const float* __restrict__ mask, const unsigned* __restrict__ flag)
{
  constexpr int N = 2048;
  __shared__ u16 sK[2][2][4096];   // [group][buf][64 keys][64 d], chunk-swizzled
  __shared__ u16 sV[2][2][4096];   // [group][buf][64 d][64 keys] (V^T)
  __shared__ float2 sStats[256];   // [wq*64 + lane] = {m, lsum} from group 1

  const int tid  = threadIdx.x;
  const int lane = tid & 63;
  const int wave = tid >> 6;
  const int g    = wave >> 2;      // KV-parity group
  const int wq   = wave & 3;       // q-sub-tile within block
  const int ltid = tid & 255;      // thread id within group (for staging)
  const int l31  = lane & 31;
  const int hi   = lane >> 5;

  const int bid  = blockIdx.x;
  const int xcd  = bid & 7, slot = bid >> 3;
  const int bh   = xcd + 8 * (slot >> 4);      // 4 bh per XCD -> KV L2-resident
  const int qt   = slot & 15;
  const int b    = bh >> 4, h = bh & 15;

  const u16* Kbh = kb  + (size_t)bh * N * 64;
  const u16* Vbh = vtb + (size_t)bh * 64 * N;
  const int q_lo = qt * 128 + wq * 32;
  const int qg   = q_lo + l31;

  // Q B-frag: lane holds Q[q=l31][d = ks*16 + hi*8 + j]
  bf16x8 qf[4];
  {
    const u16* qrow = qb + ((size_t)bh * N + qg) * 64;
#pragma unroll
    for (int ks = 0; ks < 4; ++ks)
      qf[ks] = *(const bf16x8*)(qrow + ks * 16 + hi * 8);
  }

  const unsigned use_mask = *flag;
  const float* maskb = mask + (size_t)b * N * N;

  float m_run = -INFINITY, lsum = 0.f;
  f32x16 o0, o1;
#pragma unroll
  for (int r = 0; r < 16; ++r) { o0[r] = 0.f; o1[r] = 0.f; }

  auto stage = [&](int buf, int kt) {
#pragma unroll
    for (int j = 0; j < 2; ++j) {
      int off = (ltid + j * 256) << 4;
      int row = off >> 7;
      int ch  = (off & 127) >> 4;
      int gch = ch ^ (row & 7);
      async_cp16((char*)&sK[g][buf][0] + off,
                 (const char*)Kbh + (size_t)(kt * 64 + row) * 128 + gch * 16);
      async_cp16((char*)&sV[g][buf][0] + off,
                 (const char*)Vbh + (size_t)row * (N * 2) + (size_t)kt * 128 + gch * 16);
    }
  };

  stage(0, g);          // group g's first tile: kt = g
  __syncthreads();

  const float L2E = 1.44269504088896340736f;

  for (int t = 0; t < 16; ++t) {
    const int kt  = 2 * t + g;
    const int cur = t & 1;
    if (t + 1 < 16) stage(cur ^ 1, kt + 2);

    const char* kbase = (const char*)&sK[g][cur][0];
    const char* vbase = (const char*)&sV[g][cur][0];

    // S^T: 2 key-blocks of 32, 4 k-slices of d each
    f32x16 sc0, sc1;
#pragma unroll
    for (int r = 0; r < 16; ++r) { sc0[r] = 0.f; sc1[r] = 0.f; }

    __builtin_amdgcn_s_setprio(1);
#pragma unroll
    for (int ks = 0; ks < 4; ++ks) {
      int row0 = l31;
      int a0 = (row0 << 7) + ((((ks << 1) + hi) ^ (row0 & 7)) << 4);
      bf16x8 kf0 = *(const bf16x8*)(kbase + a0);
      sc0 = __builtin_amdgcn_mfma_f32_32x32x16_bf16(kf0, qf[ks], sc0, 0, 0, 0);
      int row1 = 32 + l31;
      int a1 = (row1 << 7) + ((((ks << 1) + hi) ^ (row1 & 7)) << 4);
      bf16x8 kf1 = *(const bf16x8*)(kbase + a1);
      sc1 = __builtin_amdgcn_mfma_f32_32x32x16_bf16(kf1, qf[ks], sc1, 0, 0, 0);
    }
    __builtin_amdgcn_s_setprio(0);

    if (use_mask) {                      // slow path only if mask != 0
#pragma unroll
      for (int r = 0; r < 16; ++r) {
        int krow = (r & 3) + 8 * (r >> 2) + 4 * hi;
        sc0[r] += maskb[(size_t)qg * N + kt * 64 + krow];
        sc1[r] += maskb[(size_t)qg * N + kt * 64 + 32 + krow];
      }
    }

    // row max over 64 keys: balanced in-lane tree + xor32
    float tmx[8];
#pragma unroll
    for (int r = 0; r < 8; ++r)
      tmx[r] = fmaxf(fmaxf(sc0[r], sc0[r + 8]), fmaxf(sc1[r], sc1[r + 8]));
#pragma unroll
    for (int r = 0; r < 4; ++r) tmx[r] = fmaxf(tmx[r], tmx[r + 4]);
    float pm = fmaxf(fmaxf(tmx[0], tmx[1]), fmaxf(tmx[2], tmx[3]));
    pm = fmaxf(pm, __shfl_xor(pm, 32, 64));

    // defer-max (T13): rescale only when running max grows past THR=8
    if (__any(pm > m_run + 8.f)) {
      const float m_new = fmaxf(m_run, pm);
      const float f = __builtin_amdgcn_exp2f((m_run - m_new) * L2E);
      m_run = m_new;
      float fr[16];
#pragma unroll
      for (int r = 0; r < 16; ++r)
        fr[r] = __shfl(f, (r & 3) + 8 * (r >> 2) + 4 * hi, 64);
#pragma unroll
      for (int r = 0; r < 16; ++r) { o0[r] *= fr[r]; o1[r] *= fr[r]; }
      lsum *= f;
    }

    // p = exp(s - m) in place; 4-way partial sums
    const float mL2 = m_run * L2E;
    float rs0 = 0.f, rs1 = 0.f, rs2 = 0.f, rs3 = 0.f;
#pragma unroll
    for (int r = 0; r < 16; r += 4) {
      sc0[r]   = __builtin_amdgcn_exp2f(__builtin_fmaf(sc0[r],   L2E, -mL2));
      sc0[r+1] = __builtin_amdgcn_exp2f(__builtin_fmaf(sc0[r+1], L2E, -mL2));
      sc0[r+2] = __builtin_amdgcn_exp2f(__builtin_fmaf(sc0[r+2], L2E, -mL2));
      sc0[r+3] = __builtin_amdgcn_exp2f(__builtin_fmaf(sc0[r+3], L2E, -mL2));
      sc1[r]   = __builtin_amdgcn_exp2f(__builtin_fmaf(sc1[r],   L2E, -mL2));
      sc1[r+1] = __builtin_amdgcn_exp2f(__builtin_fmaf(sc1[r+1], L2E, -mL2));
      sc1[r+2] = __builtin_amdgcn_exp2f(__builtin_fmaf(sc1[r+2], L2E, -mL2));
      sc1[r+3] = __builtin_amdgcn_exp2f(__builtin_fmaf(sc1[r+3], L2E, -mL2));
      rs0 += sc0[r]   + sc1[r];
      rs1 += sc0[r+1] + sc1[r+1];
      rs2 += sc0[r+2] + sc1[r+2];
      rs3 += sc0[r+3] + sc1[r+3];
    }
    float rs = (rs0 + rs1) + (rs2 + rs3);
    rs += __shfl_xor(rs, 32, 64);
    lsum += rs;

    // pack pairs
    unsigned P32_0[8], P32_1[8];
#pragma unroll
    for (int tt = 0; tt < 8; ++tt) {
      P32_0[tt] = pack2(sc0[2 * tt], sc0[2 * tt + 1]);
      P32_1[tt] = pack2(sc1[2 * tt], sc1[2 * tt + 1]);
    }

    // redistribute to PV A-frag via permlane32_swap
    bf16x8 pa[4];
#pragma unroll
    for (int ks16 = 0; ks16 < 4; ++ks16) {
      const int b4 = (ks16 & 1) << 2;
      unsigned c0, c1, c2, c3;
      if (ks16 < 2) { c0 = P32_0[b4]; c2 = P32_0[b4+2]; c1 = P32_0[b4+1]; c3 = P32_0[b4+3]; }
      else          { c0 = P32_1[b4]; c2 = P32_1[b4+2]; c1 = P32_1[b4+1]; c3 = P32_1[b4+3]; }
      asm volatile("v_permlane32_swap_b32 %0, %1" : "+v"(c0), "+v"(c2));
      asm volatile("v_permlane32_swap_b32 %0, %1" : "+v"(c1), "+v"(c3));
      u32x4v w; w[0] = c0; w[1] = c1; w[2] = c2; w[3] = c3;
      pa[ks16] = __builtin_bit_cast(bf16x8, w);
    }

    // O += P * V
    __builtin_amdgcn_s_setprio(1);
#pragma unroll
    for (int ks16 = 0; ks16 < 4; ++ks16) {
      int row0 = l31;
      int a0 = (row0 << 7) + ((((ks16 << 1) + hi) ^ (row0 & 7)) << 4);
      bf16x8 vf0 = *(const bf16x8*)(vbase + a0);
      o0 = __builtin_amdgcn_mfma_f32_32x32x16_bf16(pa[ks16], vf0, o0, 0, 0, 0);
      int row1 = 32 + l31;
      int a1 = (row1 << 7) + ((((ks16 << 1) + hi) ^ (row1 & 7)) << 4);
      bf16x8 vf1 = *(const bf16x8*)(vbase + a1);
      o1 = __builtin_amdgcn_mfma_f32_32x32x16_bf16(pa[ks16], vf1, o1, 0, 0, 0);
    }
    __builtin_amdgcn_s_setprio(0);

    __syncthreads();
  }

  // ---- flash-combine: group 1 publishes (O, m, l); group 0 merges + stores ----
  // Merge area reuses group 1's staging LDS (disjoint from group 0's buffers).
  // Lane-matched layout: wave wq of both groups hold the SAME (q,d) per (lane,reg).
  const int sw = lane & 7;   // chunk swizzle (same formula both sides)
  {
    float* R = (wq < 2) ? ((float*)&sK[1][0][0] + ((wq & 1) * 64 + lane) * 32)
                        : ((float*)&sV[1][0][0] + ((wq & 1) * 64 + lane) * 32);
    if (g == 1) {
      sStats[wq * 64 + lane] = make_float2(m_run, lsum);
#pragma unroll
      for (int i = 0; i < 4; ++i) {
        f32x4 tv; tv[0]=o0[4*i]; tv[1]=o0[4*i+1]; tv[2]=o0[4*i+2]; tv[3]=o0[4*i+3];
        *(f32x4*)(R + 4 * (i ^ sw)) = tv;
      }
#pragma unroll
      for (int i = 0; i < 4; ++i) {
        f32x4 tv; tv[0]=o1[4*i]; tv[1]=o1[4*i+1]; tv[2]=o1[4*i+2]; tv[3]=o1[4*i+3];
        *(f32x4*)(R + 4 * ((i + 4) ^ sw)) = tv;
      }
    }
    __syncthreads();
    if (g == 0) {
      float2 s1 = sStats[wq * 64 + lane];
      float mf = fmaxf(m_run, s1.x);
      float ea = __builtin_amdgcn_exp2f((m_run - mf) * L2E);
      float eb = __builtin_amdgcn_exp2f((s1.x  - mf) * L2E);
      float lf = __builtin_fmaf(lsum, ea, s1.y * eb);
      float ai = ea / lf, bi = eb / lf;
      f32x4 c[8];
#pragma unroll
      for (int i = 0; i < 8; ++i) c[i] = *(const f32x4*)(R + 4 * (i ^ sw));
#pragma unroll
      for (int r = 0; r < 16; ++r) {
        int idx = (r & 3) + 8 * (r >> 2) + 4 * hi;
        float Ar = __shfl(ai, idx, 64);
        float Br = __shfl(bi, idx, 64);
        float v0 = __builtin_fmaf(o0[r], Ar, c[r >> 2][r & 3] * Br);
        float v1 = __builtin_fmaf(o1[r], Ar, c[4 + (r >> 2)][r & 3] * Br);
        int qrow = q_lo + idx;
        size_t base = ((size_t)(b * N + qrow)) * 1024 + h * 64;
        ao[base + l31]      = tobf(v0);
        ao[base + 32 + l31] = tobf(v1);
      }
    }
  }
}

// ---------------- launch ----------------
extern "C" void kernel_launch(void* const* d_in, const int* in_sizes, int n_in,
                              void* d_out, int out_size, void* d_ws, size_t ws_size,
                              hipStream_t stream) {
  const float* x      = (const float*)d_in[0];
  const float* mask   = (const float*)d_in[1];
  const float* w_qkv  = (const float*)d_in[2];
  const float* q_bias = (const float*)d_in[3];
  const float* k_bias = (const float*)d_in[4];
  const float* v_bias = (const float*)d_in[5];
  const float* w_proj = (const float*)d_in[6];
  const float* b_proj = (const float*)d_in[7];
  float* out = (float*)d_out;

  const int B = 2, N = 2048, C = 1024;
  const int M = B * N;                       // 4096

  // workspace layout (u16 units)
  u16* ws     = (u16*)d_ws;
  u16* xb     = ws;                          // 4096*1024 (x bf16; reused as attn_out)
  u16* wqkvb  = ws + 4194304;                // 3072*1024
  u16* wprojb = ws + 7340032;                // 1024*1024
  u16* qbuf   = ws + 8388608;                // 32*2048*64
  u16* kbuf   = ws + 12582912;
  u16* vtbuf  = ws + 16777216;               // [b,h,d,n]
  unsigned* flag = (unsigned*)(ws + 20971520);
  u16* aob    = xb;                          // reuse: x dead after QKV GEMM

  k_zero_flag<<<1, 64, 0, stream>>>(flag);
  k_pre<<<2048, 256, 0, stream>>>(x, w_qkv, w_proj, xb, wqkvb, wprojb,
                                  (const u32x4v*)mask, flag);

  k_gemm_nt<0><<<(M / 128) * (3 * C / 128), 256, 0, stream>>>(
      xb, wqkvb, 3 * C, C, 3 * C / 128,
      q_bias, k_bias, v_bias, qbuf, kbuf, vtbuf, nullptr, nullptr);

  k_attn<<<B * 16 * (N / 128), 512, 0, stream>>>(qbuf, kbuf, vtbuf, aob, mask, flag);

  k_gemm_nt<1><<<(M / 128) * (C / 128), 256, 0, stream>>>(
      aob, wprojb, C, C, C / 128,
      nullptr, nullptr, nullptr, nullptr, nullptr, nullptr, out, b_proj);
}